// Round 5
// baseline (266.264 us; speedup 1.0000x reference)
//
#include <hip/hip_runtime.h>

// Problem constants (from reference)
#define BB 16
#define LL 100
#define HH 1024
#define WW 1024
#define NC 3
#define R2 10                 // RADIUS // 2
#define WIN_I 21              // 2*R2 + 1   (di in [-10, 10])
#define WIN_J 20              // 2*R2       (dj in [-10, 9], faithful asymmetry)
#define WIN (WIN_I * WIN_J)   // 420
// SIGMA = RADIUS//3 = 7 ; gauss = exp(-0.5*(di^2+dj^2)/49)
#define INV_2SIG2 (0.5f / 49.0f)
// log_softmax(one_hot) true-class constant: ce = log(e+2) - p_true
#define LSE_CONST 1.5514447139320511f

#define BLOCK1 448            // 7 waves >= 420 window elements (1 elem/thread)

__global__ __launch_bounds__(BLOCK1) void point_ce_partials(
    const float* __restrict__ y_pred,      // [B][3][H][W]
    const int*   __restrict__ y_true,      // [B][1][H][W]
    const int*   __restrict__ points,      // [B][L][2]  (i, j)
    const int*   __restrict__ point_labels,// [B][L][1]
    float*       __restrict__ partials)    // [B*L]
{
    const int pt = blockIdx.x;             // 0 .. B*L-1
    const int b  = pt / LL;

    // Wave-uniform point metadata (compiler scalarizes via readfirstlane)
    const int pi  = points[pt * 2 + 0];
    const int pj  = points[pt * 2 + 1];
    const int lab = point_labels[pt];

    const size_t HW = (size_t)HH * WW;
    const int*   yt_base = y_true + (size_t)b * HW;
    const float* yp_base = y_pred + (size_t)b * NC * HW;

    float acc = 0.0f;

    const int idx = threadIdx.x;           // one window element per thread
    if (idx < WIN) {
        const int qi = idx / WIN_J;             // 0..20  (window row)
        const int di = qi - R2;                 // -10..10
        const int dj = (idx - qi * WIN_J) - R2; // -10..9
        const int ii = pi + di;
        const int jj = pj + dj;
        const bool valid = (ii >= 0) & (ii < HH) & (jj >= 0) & (jj < WW);

        // Clamp for addressing (reference semantics); predicate the accumulate.
        const int ic = min(max(ii, 0), HH - 1);
        const int jc = min(max(jj, 0), WW - 1);
        const size_t pix = (size_t)ic * WW + jc;

        // Issue all four gathers unconditionally -> they overlap (1x latency,
        // not a yt -> compare -> yp dependent chain).
        const int   yt = yt_base[pix];
        const float x0 = yp_base[pix];
        const float x1 = yp_base[pix + HW];
        const float x2 = yp_base[pix + 2 * HW];

        // Gaussian weight (overlaps with memory latency)
        const float g = expf(-(float)(di * di + dj * dj) * INV_2SIG2);

        // 3-class softmax -> probability of the true class
        const float m  = fmaxf(x0, fmaxf(x1, x2));
        const float e0 = expf(x0 - m);
        const float e1 = expf(x1 - m);
        const float e2 = expf(x2 - m);
        const float den = e0 + e1 + e2;
        const float et  = (lab == 0) ? e0 : (lab == 1) ? e1 : e2;
        const float val = g * (LSE_CONST - et / den);   // ce = log(e+2) - p_true

        acc = (valid && (yt == lab)) ? val : 0.0f;
    }

    // 64-lane wave reduction
    #pragma unroll
    for (int off = 32; off > 0; off >>= 1)
        acc += __shfl_down(acc, off, 64);

    __shared__ float s[BLOCK1 / 64];
    const int wave = threadIdx.x >> 6;
    const int lane = threadIdx.x & 63;
    if (lane == 0) s[wave] = acc;
    __syncthreads();
    if (threadIdx.x == 0) {
        float t = 0.0f;
        #pragma unroll
        for (int w = 0; w < BLOCK1 / 64; ++w) t += s[w];
        partials[pt] = t;                  // every block writes its own slot: no ws init needed
    }
}

__global__ __launch_bounds__(256) void point_ce_reduce(
    const float* __restrict__ partials,    // [B*L]
    float*       __restrict__ out)         // [1]
{
    double acc = 0.0;
    for (int i = threadIdx.x; i < BB * LL; i += 256)
        acc += (double)partials[i];

    #pragma unroll
    for (int off = 32; off > 0; off >>= 1)
        acc += __shfl_down(acc, off, 64);

    __shared__ double s[4];
    const int wave = threadIdx.x >> 6;
    const int lane = threadIdx.x & 63;
    if (lane == 0) s[wave] = acc;
    __syncthreads();
    if (threadIdx.x == 0) {
        const double total = s[0] + s[1] + s[2] + s[3];
        out[0] = (float)(total / (double)((size_t)BB * HH * WW));
    }
}

extern "C" void kernel_launch(void* const* d_in, const int* in_sizes, int n_in,
                              void* d_out, int out_size, void* d_ws, size_t ws_size,
                              hipStream_t stream) {
    const float* y_pred       = (const float*)d_in[0];
    const int*   y_true       = (const int*)  d_in[1];
    const int*   points       = (const int*)  d_in[2];
    const int*   point_labels = (const int*)  d_in[3];
    float*       out          = (float*)d_out;
    float*       partials     = (float*)d_ws;   // B*L floats

    point_ce_partials<<<BB * LL, BLOCK1, 0, stream>>>(y_pred, y_true, points, point_labels, partials);
    point_ce_reduce<<<1, 256, 0, stream>>>(partials, out);
}